// Round 14
// baseline (576.786 us; speedup 1.0000x reference)
//
#include <hip/hip_runtime.h>
#include <cstdint>
#include <cstddef>

// ============================================================================
// SSD forward (image 7 only) + NMS, all fp32.
// R13: R12 (best, 398.2us) + weights moved from SMEM (s_load) to per-lane
// VMEM broadcast loads: dropped readfirstlane on the co-group index so the
// compiler's divergence analysis emits global_load_dwordx4 (same addr across
// lanes = HW broadcast). Rationale: SMEM returns out-of-order on gfx9-lineage
// -> every weight-dependent wait is lgkmcnt(0), draining ALL outstanding
// ds_reads; VMEM weights wait on in-order vmcnt(N), decoupled from the DS
// counter. __launch_bounds__(256,4) caps VGPR<=128 (16 waves/CU preserved).
// Accumulation order (ci,kh,kw) ci-asc unchanged — exact R0 numerics (11x).
// ============================================================================

// ---------------- fused weight repack ----------------------------------------
__global__ __launch_bounds__(256) void k_repack_all(
    const float* __restrict__ w2, const float* __restrict__ w3,
    const float* __restrict__ w4, const float* __restrict__ regw,
    const float* __restrict__ clsw, float* __restrict__ wr2,
    float* __restrict__ wr3, float* __restrict__ wr4, float* __restrict__ wh) {
  int idx = blockIdx.x * 256 + threadIdx.x;
  if (idx < 73728) {  // conv2: CIN=64 COUT=128
    int co = idx % 128, r = idx / 128, ci = r / 9, tap = r % 9;
    wr2[idx] = w2[(co * 64 + ci) * 9 + tap];
  } else if (idx < 73728 + 294912) {  // conv3: CIN=128 COUT=256
    int i = idx - 73728;
    int co = i % 256, r = i / 256, ci = r / 9, tap = r % 9;
    wr3[i] = w3[(co * 128 + ci) * 9 + tap];
  } else if (idx < 73728 + 294912 + 589824) {  // conv4: CIN=256 COUT=256
    int i = idx - (73728 + 294912);
    int co = i % 256, r = i / 256, ci = r / 9, tap = r % 9;
    wr4[i] = w4[(co * 256 + ci) * 9 + tap];
  } else if (idx < 73728 + 294912 + 589824 + 57600) {  // head
    int i = idx - (73728 + 294912 + 589824);
    int ci = i & 255, r = i >> 8, tap = r / 25, o = r % 25;
    wh[i] = (o < 4) ? regw[(o * 256 + ci) * 9 + tap]
                    : clsw[((o - 4) * 256 + ci) * 9 + tap];
  }
}

// ---------------- conv1: 3->64, 512->256, stride 2, co-split by blockIdx.z ---
__global__ __launch_bounds__(256) void k_conv1(const float* __restrict__ x,
                                               const float* __restrict__ w,
                                               const float* __restrict__ b,
                                               float* __restrict__ out) {
  __shared__ float in_t[3][33][33];
  const int tx = threadIdx.x, ty = threadIdx.y;
  const int tid = ty * 16 + tx;
  const int ox0 = blockIdx.x * 16, oy0 = blockIdx.y * 16;
  const int co0 = blockIdx.z * 16;
  for (int idx = tid; idx < 3 * 33 * 33; idx += 256) {
    int ci = idx / 1089, rem = idx % 1089;
    int r = rem / 33, c = rem % 33;
    int iy = oy0 * 2 + r, ix = ox0 * 2 + c;
    float v = 0.f;
    if (iy < 512 && ix < 512) v = x[(size_t)ci * 262144 + iy * 512 + ix];
    in_t[ci][r][c] = v;
  }
  __syncthreads();
  float rin[27];
#pragma unroll
  for (int ci = 0; ci < 3; ++ci)
#pragma unroll
    for (int kh = 0; kh < 3; ++kh)
#pragma unroll
      for (int kw = 0; kw < 3; ++kw)
        rin[ci * 9 + kh * 3 + kw] = in_t[ci][2 * ty + kh][2 * tx + kw];
  const int oy = oy0 + ty, ox = ox0 + tx;
  for (int co = co0; co < co0 + 16; ++co) {  // co uniform -> weights via s_load
    float a = 0.f;
#pragma unroll
    for (int k = 0; k < 27; ++k) a = fmaf(w[co * 27 + k], rin[k], a);
    out[(size_t)co * 65536 + oy * 256 + ox] = fmaxf(a + b[co], 0.f);
  }
}

// ---------------- generic stride-2 3x3 conv, SAME(pad lo 0 hi 1) -------------
// NW waves = NW co-groups x 64 lanes. Lane lp -> (py=lp/SW, px=lp%SW).
// LDS row layout: [EV: SW+1 even cols | OD: SW odd cols | pad] = ROWW words.
// ROWW: (2*ROWW mod 32)==8 -> lanes hit every bank exactly 2x (free).
// Weights: per-lane VMEM broadcast (gu NOT readfirstlane'd -> divergent addr
// -> global_load_dwordx4, vmcnt-tracked, decoupled from ds_read lgkmcnt).
// Per-output accumulation order: tap 0..8 = (kh,kw) lexicographic, ci asc.
template <int CIN, int COUT, int HIN, int WIN, int SH, int SW, int COPT,
          int CIT, int KSPLIT, int ROWW, int NW>
__global__ __launch_bounds__(NW * 64, 4) void conv_s2(
    const float* __restrict__ in, const float* __restrict__ wr,
    const float* __restrict__ bias, float* __restrict__ out) {
  constexpr int HOUT = HIN / 2, WOUT = WIN / 2;
  constexpr int IH = SH * 2 + 1, IW = SW * 2 + 1;
  constexpr int EVW = SW + 1;
  constexpr int COT = NW * COPT;
  constexpr int NPAIR = CIT * IH * EVW;
  constexpr int NTHR = NW * 64;
  static_assert(SH * SW == 64, "one position per lane");
  static_assert(EVW + SW < ROWW + 1, "pad slot fits");
  __shared__ float lds[CIT * IH * ROWW];

  const int tid = threadIdx.x;
  const int gu  = tid >> 6;   // per-lane (divergent to compiler) -> VMEM weights
  const int lp  = tid & 63;
  const int py  = lp / SW, px = lp % SW;

  constexpr int ntx = WOUT / SW;
  const int bx = blockIdx.x % ntx, by = blockIdx.x / ntx;
  const int ox0 = bx * SW, oy0 = by * SH;
  const int co_blk = blockIdx.y * COT;
  const int cobase = co_blk + gu * COPT;
  const int ci_begin = (KSPLIT > 1) ? blockIdx.z * (CIN / KSPLIT) : 0;
  constexpr int NST = (CIN / KSPLIT) / CIT;

  float acc[COPT] = {};

  for (int st = 0; st < NST; ++st) {
    const int cib = ci_begin + st * CIT;
    if (st) __syncthreads();   // protect previous stage's reads
    // ---- staging: global float2 pairs -> interleaved EV|OD row layout ----
    for (int idx = tid; idx < NPAIR; idx += NTHR) {
      int ci = idx / (IH * EVW), rem = idx % (IH * EVW);
      int r = rem / EVW, c2 = rem % EVW;
      int iy = oy0 * 2 + r, ix = ox0 * 2 + 2 * c2;
      float v0 = 0.f, v1 = 0.f;
      const float* src = in + (size_t)(cib + ci) * HIN * WIN;
      if (iy < HIN) {
        if ((2 * c2 + 1 < IW) && (ix + 1 < WIN)) {
          float2 t = *(const float2*)(src + (size_t)iy * WIN + ix);
          v0 = t.x; v1 = t.y;
        } else if (ix < WIN) {
          v0 = src[(size_t)iy * WIN + ix];
        }
      }
      int rb = (ci * IH + r) * ROWW;
      lds[rb + c2] = v0;            // even col c2
      lds[rb + EVW + c2] = v1;      // odd col c2 (c2==SW -> pad slot)
    }
    __syncthreads();
    // ---- compute: 9 taps per ci from one base addr ----
#pragma unroll 2
    for (int ci = 0; ci < CIT; ++ci) {
      const int b0 = (ci * IH + 2 * py) * ROWW + px;
      float e00 = lds[b0];               // (kh0,kw0) col 2px
      float q0  = lds[b0 + EVW];         // (kh0,kw1) col 2px+1
      float e01 = lds[b0 + 1];           // (kh0,kw2) col 2px+2
      float e10 = lds[b0 + ROWW];
      float q1  = lds[b0 + ROWW + EVW];
      float e11 = lds[b0 + ROWW + 1];
      float e20 = lds[b0 + 2 * ROWW];
      float q2  = lds[b0 + 2 * ROWW + EVW];
      float e21 = lds[b0 + 2 * ROWW + 1];
      const float* wp = wr + (size_t)(cib + ci) * 9 * COUT + cobase;
#pragma unroll
      for (int c = 0; c < COPT; ++c) acc[c] = fmaf(e00, wp[c], acc[c]);
#pragma unroll
      for (int c = 0; c < COPT; ++c) acc[c] = fmaf(q0, wp[COUT + c], acc[c]);
#pragma unroll
      for (int c = 0; c < COPT; ++c) acc[c] = fmaf(e01, wp[2 * COUT + c], acc[c]);
#pragma unroll
      for (int c = 0; c < COPT; ++c) acc[c] = fmaf(e10, wp[3 * COUT + c], acc[c]);
#pragma unroll
      for (int c = 0; c < COPT; ++c) acc[c] = fmaf(q1, wp[4 * COUT + c], acc[c]);
#pragma unroll
      for (int c = 0; c < COPT; ++c) acc[c] = fmaf(e11, wp[5 * COUT + c], acc[c]);
#pragma unroll
      for (int c = 0; c < COPT; ++c) acc[c] = fmaf(e20, wp[6 * COUT + c], acc[c]);
#pragma unroll
      for (int c = 0; c < COPT; ++c) acc[c] = fmaf(q2, wp[7 * COUT + c], acc[c]);
#pragma unroll
      for (int c = 0; c < COPT; ++c) acc[c] = fmaf(e21, wp[8 * COUT + c], acc[c]);
    }
  }

  const int oy = oy0 + py, ox = ox0 + px;
#pragma unroll
  for (int c = 0; c < COPT; ++c) {
    int co = cobase + c;
    if constexpr (KSPLIT > 1) {
      out[((size_t)blockIdx.z * COUT + co) * (HOUT * WOUT) + oy * WOUT + ox] =
          acc[c];
    } else {
      out[(size_t)co * (HOUT * WOUT) + oy * WOUT + ox] =
          fmaxf(acc[c] + bias[co], 0.f);
    }
  }
}

// ---------------- combine conv4 K-split partials + bias + relu, write NHWC ---
// EXACT R0 semantics: v = ((p0+p1)+p2)+p3; out = max(v+b, 0)
__global__ __launch_bounds__(256) void k_combine(const float* __restrict__ part,
                                                 const float* __restrict__ b,
                                                 float* __restrict__ h4t) {
  int co = blockIdx.x;  // 0..255
  float bb = b[co];
  for (int k2 = 0; k2 < 4; ++k2) {
    int pos = threadIdx.x + k2 * 256;
    float v = part[(size_t)(0 * 256 + co) * 1024 + pos] +
              part[(size_t)(1 * 256 + co) * 1024 + pos] +
              part[(size_t)(2 * 256 + co) * 1024 + pos] +
              part[(size_t)(3 * 256 + co) * 1024 + pos];
    h4t[(size_t)pos * 256 + co] = fmaxf(v + bb, 0.f);
  }
}

// ---------------- head: reg(4)+cls(21) stride-1 conv + softmax/max/argmax ----
__global__ __launch_bounds__(256) void k_head(const float* __restrict__ h4t,
                                              const float* __restrict__ wh,
                                              const float* __restrict__ regb,
                                              const float* __restrict__ clsb,
                                              float* __restrict__ locs,
                                              float* __restrict__ confs,
                                              float* __restrict__ scores,
                                              float* __restrict__ labelsF) {
  const int pos = blockIdx.x;
  const int py = pos >> 5, px = pos & 31;
  const int t = threadIdx.x;
  float part[25] = {};
#pragma unroll
  for (int kh = 0; kh < 3; ++kh) {
    int iy = py + kh - 1;
    if (iy < 0 || iy > 31) continue;  // block-uniform
#pragma unroll
    for (int kw = 0; kw < 3; ++kw) {
      int ix = px + kw - 1;
      if (ix < 0 || ix > 31) continue;
      int tap = kh * 3 + kw;
      float v = h4t[(size_t)(iy * 32 + ix) * 256 + t];
      const float* wp = wh + (size_t)tap * 25 * 256 + t;
#pragma unroll
      for (int o = 0; o < 25; ++o)
        part[o] = fmaf(v, wp[(size_t)o * 256], part[o]);
    }
  }
#pragma unroll
  for (int o = 0; o < 25; ++o) {
#pragma unroll
    for (int d = 1; d < 64; d <<= 1) part[o] += __shfl_xor(part[o], d);
  }
  __shared__ float red[4][25];
  __shared__ float yv[25];
  const int wv = t >> 6, ln = t & 63;
  if (ln == 0) {
#pragma unroll
    for (int o = 0; o < 25; ++o) red[wv][o] = part[o];
  }
  __syncthreads();
  if (t < 25) {
    float y = red[0][t] + red[1][t] + red[2][t] + red[3][t];
    y += (t < 4) ? regb[t] : clsb[t - 4];
    if (t < 4) locs[(size_t)pos * 4 + t] = y;
    else       confs[(size_t)pos * 21 + (t - 4)] = y;
    yv[t] = y;
  }
  __syncthreads();
  if (t == 0) {
    float m = yv[4];
    int lab = 0;
    for (int j = 1; j < 21; ++j)
      if (yv[4 + j] > m) { m = yv[4 + j]; lab = j; }  // first-max semantics
    float s = 0.f;
    for (int j = 0; j < 21; ++j) s += expf(yv[4 + j] - m);
    scores[pos] = 1.f / s;   // max softmax prob
    labelsF[pos] = (float)lab;
  }
}

// ---------------- stable descending bitonic sort of 1024 scores --------------
__global__ __launch_bounds__(512) void k_sort(const float* __restrict__ scores,
                                              const float* __restrict__ locs,
                                              int* __restrict__ order,
                                              float* __restrict__ ssc,
                                              float* __restrict__ bsrt,
                                              unsigned long long* __restrict__ vbits) {
  __shared__ float sk[1024];
  __shared__ int   si[1024];
  const int t = threadIdx.x;
  sk[t] = scores[t];           si[t] = t;
  sk[t + 512] = scores[t + 512]; si[t + 512] = t + 512;
  for (int k = 2; k <= 1024; k <<= 1) {
    for (int j = k >> 1; j > 0; j >>= 1) {
      __syncthreads();
      int i1 = ((t / j) * (2 * j)) + (t % j);
      int i2 = i1 + j;
      bool up = (i1 & k) == 0;
      float sa = sk[i1], sb = sk[i2];
      int ia = si[i1], ib = si[i2];
      bool b_before_a = (sb > sa) || (sb == sa && ib < ia);
      bool a_before_b = (sa > sb) || (sa == sb && ia < ib);
      bool sw = up ? b_before_a : a_before_b;
      if (sw) { sk[i1] = sb; sk[i2] = sa; si[i1] = ib; si[i2] = ia; }
    }
  }
  __syncthreads();
  for (int i = t; i < 1024; i += 512) {
    int oi = si[i];
    order[i] = oi;
    ssc[i] = sk[i];
    ((float4*)bsrt)[i] = ((const float4*)locs)[oi];
  }
  if (t < 16) {  // validity bits (score > SCORE_THR), sorted order
    unsigned long long w = 0;
    for (int b2 = 0; b2 < 64; ++b2)
      if (sk[t * 64 + b2] > 0.04f) w |= (1ull << b2);
    vbits[t] = w;
  }
}

// ---------------- pairwise IoU suppression bitmask (1024x1024 bits) ----------
__global__ __launch_bounds__(256) void k_mask(const float* __restrict__ bsrt,
                                              unsigned long long* __restrict__ mask) {
  __shared__ float4 sb[1024];
  const int t = threadIdx.x;
  for (int idx = t; idx < 1024; idx += 256)
    sb[idx] = ((const float4*)bsrt)[idx];
  __syncthreads();
  const int i = blockIdx.x * 16 + (t & 15);
  const int w = t >> 4;
  float4 bi = sb[i];
  float ai = (bi.z - bi.x) * (bi.w - bi.y);
  unsigned long long bits = 0;
  for (int jj = 0; jj < 64; ++jj) {
    float4 bj = sb[w * 64 + jj];
    float aj = (bj.z - bj.x) * (bj.w - bj.y);
    float ltx = fmaxf(bi.x, bj.x), lty = fmaxf(bi.y, bj.y);
    float rbx = fminf(bi.z, bj.z), rby = fminf(bi.w, bj.w);
    float inter = fmaxf(rbx - ltx, 0.f) * fmaxf(rby - lty, 0.f);
    float uni = ai + aj - inter;
    float iou = inter / (uni + 1e-9f);
    if (iou > 0.5f) bits |= (1ull << jj);
  }
  mask[(size_t)i * 16 + w] = bits;
}

// ---------------- parallel fixpoint greedy NMS + fused gather ----------------
__global__ __launch_bounds__(1024) void k_nms_gather(
    const unsigned long long* __restrict__ mask,
    const unsigned long long* __restrict__ vbits,
    const int* __restrict__ order, const float* __restrict__ ssc,
    const float* __restrict__ locs, const float* __restrict__ confs,
    const float* __restrict__ labelsF, float* __restrict__ out) {
  __shared__ unsigned long long KEEP[16], DEAD[16];
  __shared__ int ncert;
  const int i = threadIdx.x;        // box index (sorted order)
  const int w = i >> 6, l = i & 63; // wave, lane

  unsigned long long R[16];
#pragma unroll
  for (int k = 0; k < 16; ++k) {
    unsigned long long m = 0;
    if (k < w) m = mask[(size_t)i * 16 + k];
    else if (k == w && l) m = mask[(size_t)i * 16 + k] & ((1ull << l) - 1ull);
    R[k] = m;
  }
  const bool valid = (vbits[w] >> l) & 1ull;

  if (i < 16) { KEEP[i] = 0ull; DEAD[i] = 0ull; }
  if (i == 0) ncert = 0;
  __syncthreads();

  int status = 0;  // 0 unknown, 1 kept, 2 dead
  for (;;) {
    unsigned long long s = 0, p = 0;
    if (status == 0) {
#pragma unroll
      for (int k = 0; k < 16; ++k) {
        unsigned long long K_ = KEEP[k], D_ = DEAD[k];
        s |= R[k] & K_;
        p |= R[k] & ~D_;
      }
    }
    __syncthreads();  // all reads done before any write
    bool newKeep = false, newDead = false;
    if (status == 0) {
      if (!valid)      { status = 2; newDead = true; }
      else if (s)      { status = 2; newDead = true; }
      else if (!p)     { status = 1; newKeep = true; }
    }
    unsigned long long bk = __ballot(newKeep);
    unsigned long long bd = __ballot(newDead);
    if (l == 0) {
      if (bk) KEEP[w] |= bk;
      if (bd) DEAD[w] |= bd;
      int n = __popcll(bk) + __popcll(bd);
      if (n) atomicAdd(&ncert, n);
    }
    __syncthreads();
    if (ncert >= 1024) break;
  }

  const bool kp = (status == 1);
  const int oi = order[i];
  float4 bx = kp ? ((const float4*)locs)[oi]
                 : make_float4(-1.f, -1.f, -1.f, -1.f);
  ((float4*)out)[i] = bx;
  out[4096 + i] = kp ? labelsF[oi] : 0.f;
  out[5120 + i] = kp ? ssc[i] : -1.f;
  float* oc = out + 6144 + (size_t)i * 21;
  const float* cc = confs + (size_t)oi * 21;
#pragma unroll
  for (int c = 0; c < 21; ++c) oc[c] = kp ? cc[c] : -1.f;
}

// ============================================================================
extern "C" void kernel_launch(void* const* d_in, const int* in_sizes, int n_in,
                              void* d_out, int out_size, void* d_ws, size_t ws_size,
                              hipStream_t stream) {
  const float* x    = (const float*)d_in[0] + (size_t)7 * 3 * 512 * 512;  // image 7
  const float* w1   = (const float*)d_in[1];
  const float* b1   = (const float*)d_in[2];
  const float* w2   = (const float*)d_in[3];
  const float* b2   = (const float*)d_in[4];
  const float* w3   = (const float*)d_in[5];
  const float* b3   = (const float*)d_in[6];
  const float* w4   = (const float*)d_in[7];
  const float* b4   = (const float*)d_in[8];
  const float* regw = (const float*)d_in[9];
  const float* regb = (const float*)d_in[10];
  const float* clsw = (const float*)d_in[11];
  const float* clsb = (const float*)d_in[12];
  float* out = (float*)d_out;
  char* ws = (char*)d_ws;

  // region A (0..16.8MB): h1, then part4 + h4t
  float* h1    = (float*)(ws + 0);          // 16.8MB  (dead after conv2)
  float* part4 = (float*)(ws + 0);          // 4MB     (dead after combine)
  float* h4t   = (float*)(ws + 9437184);    // 1MB
  float* h2    = (float*)(ws + 16777216);   // 8.4MB   (dead after conv3)
  float* h3    = (float*)(ws + 25165824);   // 4.2MB
  float* wr2   = (float*)(ws + 29360128);
  float* wr3   = (float*)(ws + 29655040);
  float* wr4   = (float*)(ws + 30834688);
  float* wh    = (float*)(ws + 33193984);
  float* locs  = (float*)(ws + 33424384);
  float* confs = (float*)(ws + 33440768);
  float* scores  = (float*)(ws + 33526784);
  float* labelsF = (float*)(ws + 33530880);
  int*   order   = (int*)  (ws + 33534976);
  float* ssc     = (float*)(ws + 33539072);
  float* bsrt    = (float*)(ws + 33543168);
  unsigned long long* mask  = (unsigned long long*)(ws + 33559552);
  unsigned long long* vbits = (unsigned long long*)(ws + 33690624);

  k_repack_all<<<3969, 256, 0, stream>>>(w2, w3, w4, regw, clsw,
                                         wr2, wr3, wr4, wh);

  k_conv1<<<dim3(16, 16, 4), dim3(16, 16), 0, stream>>>(x, w1, b1, h1);

  // conv2: COPT=8, 256 sp x 4 co = 1024 blocks x 256 thr, ROWW=36
  conv_s2<64, 128, 256, 256, 4, 16, 8, 16, 1, 36, 4>
      <<<dim3(256, 4, 1), 256, 0, stream>>>(h1, wr2, b2, h2);
  // conv3: COPT=4, 64 sp x 16 co = 1024 blocks, ROWW=20, 16 waves/CU
  conv_s2<128, 256, 128, 128, 8, 8, 4, 16, 1, 20, 4>
      <<<dim3(64, 16, 1), 256, 0, stream>>>(h2, wr3, b3, h3);
  // conv4: COPT=4, KSPLIT=4. 16 sp x 16 co x 4 = 1024 blocks, ROWW=20
  conv_s2<256, 256, 64, 64, 8, 8, 4, 16, 4, 20, 4>
      <<<dim3(16, 16, 4), 256, 0, stream>>>(h3, wr4, (const float*)nullptr, part4);
  k_combine<<<256, 256, 0, stream>>>(part4, b4, h4t);

  k_head<<<1024, 256, 0, stream>>>(h4t, wh, regb, clsb, locs, confs, scores, labelsF);

  k_sort<<<1, 512, 0, stream>>>(scores, locs, order, ssc, bsrt, vbits);
  k_mask<<<64, 256, 0, stream>>>(bsrt, mask);
  k_nms_gather<<<1, 1024, 0, stream>>>(mask, vbits, order, ssc, locs, confs,
                                       labelsF, out);
}

// Round 15
// 397.594 us; speedup vs baseline: 1.4507x; 1.4507x over previous
//
#include <hip/hip_runtime.h>
#include <cstdint>
#include <cstddef>

// ============================================================================
// SSD forward (image 7 only) + NMS, all fp32.
// R14: exact revert to R12 (best measured 398.2us). R13's per-lane VMEM
// weight broadcast regressed 45% — wave-uniform weights belong on the
// scalar (s_load/SQC) path; K$ broadcast is free of per-lane TA traffic.
// R12 state: COPT optimum (8/4/2 -> 113/98/120us), ROWW=20 bank-perfect
// (conflicts 1.12e7 -> 1.25e6), CIT/unroll/NW variants all measured worse.
// Accumulation order (ci,kh,kw) ci-asc — exact R0 numerics (passed 12x).
// ============================================================================

// ---------------- fused weight repack ----------------------------------------
__global__ __launch_bounds__(256) void k_repack_all(
    const float* __restrict__ w2, const float* __restrict__ w3,
    const float* __restrict__ w4, const float* __restrict__ regw,
    const float* __restrict__ clsw, float* __restrict__ wr2,
    float* __restrict__ wr3, float* __restrict__ wr4, float* __restrict__ wh) {
  int idx = blockIdx.x * 256 + threadIdx.x;
  if (idx < 73728) {  // conv2: CIN=64 COUT=128
    int co = idx % 128, r = idx / 128, ci = r / 9, tap = r % 9;
    wr2[idx] = w2[(co * 64 + ci) * 9 + tap];
  } else if (idx < 73728 + 294912) {  // conv3: CIN=128 COUT=256
    int i = idx - 73728;
    int co = i % 256, r = i / 256, ci = r / 9, tap = r % 9;
    wr3[i] = w3[(co * 128 + ci) * 9 + tap];
  } else if (idx < 73728 + 294912 + 589824) {  // conv4: CIN=256 COUT=256
    int i = idx - (73728 + 294912);
    int co = i % 256, r = i / 256, ci = r / 9, tap = r % 9;
    wr4[i] = w4[(co * 256 + ci) * 9 + tap];
  } else if (idx < 73728 + 294912 + 589824 + 57600) {  // head
    int i = idx - (73728 + 294912 + 589824);
    int ci = i & 255, r = i >> 8, tap = r / 25, o = r % 25;
    wh[i] = (o < 4) ? regw[(o * 256 + ci) * 9 + tap]
                    : clsw[((o - 4) * 256 + ci) * 9 + tap];
  }
}

// ---------------- conv1: 3->64, 512->256, stride 2, co-split by blockIdx.z ---
__global__ __launch_bounds__(256) void k_conv1(const float* __restrict__ x,
                                               const float* __restrict__ w,
                                               const float* __restrict__ b,
                                               float* __restrict__ out) {
  __shared__ float in_t[3][33][33];
  const int tx = threadIdx.x, ty = threadIdx.y;
  const int tid = ty * 16 + tx;
  const int ox0 = blockIdx.x * 16, oy0 = blockIdx.y * 16;
  const int co0 = blockIdx.z * 16;
  for (int idx = tid; idx < 3 * 33 * 33; idx += 256) {
    int ci = idx / 1089, rem = idx % 1089;
    int r = rem / 33, c = rem % 33;
    int iy = oy0 * 2 + r, ix = ox0 * 2 + c;
    float v = 0.f;
    if (iy < 512 && ix < 512) v = x[(size_t)ci * 262144 + iy * 512 + ix];
    in_t[ci][r][c] = v;
  }
  __syncthreads();
  float rin[27];
#pragma unroll
  for (int ci = 0; ci < 3; ++ci)
#pragma unroll
    for (int kh = 0; kh < 3; ++kh)
#pragma unroll
      for (int kw = 0; kw < 3; ++kw)
        rin[ci * 9 + kh * 3 + kw] = in_t[ci][2 * ty + kh][2 * tx + kw];
  const int oy = oy0 + ty, ox = ox0 + tx;
  for (int co = co0; co < co0 + 16; ++co) {  // co uniform -> weights via s_load
    float a = 0.f;
#pragma unroll
    for (int k = 0; k < 27; ++k) a = fmaf(w[co * 27 + k], rin[k], a);
    out[(size_t)co * 65536 + oy * 256 + ox] = fmaxf(a + b[co], 0.f);
  }
}

// ---------------- generic stride-2 3x3 conv, SAME(pad lo 0 hi 1) -------------
// NW waves = NW co-groups (wave-uniform cout via readfirstlane) x 64 lanes.
// Lane lp -> output position (py=lp/SW, px=lp%SW); SH*SW == 64.
// LDS row layout: [EV: SW+1 even cols | OD: SW odd cols | pad] = ROWW words.
// All 9 taps of one ci: single vaddr + const offsets -> ds_read2 merging.
// ROWW chosen so (2*ROWW mod 32) == 8 -> lanes hit every bank exactly 2x.
// Per-output accumulation order: tap 0..8 = (kh,kw) lexicographic, ci asc.
template <int CIN, int COUT, int HIN, int WIN, int SH, int SW, int COPT,
          int CIT, int KSPLIT, int ROWW, int NW>
__global__ __launch_bounds__(NW * 64) void conv_s2(
    const float* __restrict__ in, const float* __restrict__ wr,
    const float* __restrict__ bias, float* __restrict__ out) {
  constexpr int HOUT = HIN / 2, WOUT = WIN / 2;
  constexpr int IH = SH * 2 + 1, IW = SW * 2 + 1;
  constexpr int EVW = SW + 1;
  constexpr int COT = NW * COPT;
  constexpr int NPAIR = CIT * IH * EVW;
  constexpr int NTHR = NW * 64;
  static_assert(SH * SW == 64, "one position per lane");
  static_assert(EVW + SW < ROWW + 1, "pad slot fits");
  __shared__ float lds[CIT * IH * ROWW];

  const int tid = threadIdx.x;
  const int gu  = __builtin_amdgcn_readfirstlane(tid >> 6);
  const int lp  = tid & 63;
  const int py  = lp / SW, px = lp % SW;

  constexpr int ntx = WOUT / SW;
  const int bx = blockIdx.x % ntx, by = blockIdx.x / ntx;
  const int ox0 = bx * SW, oy0 = by * SH;
  const int co_blk = blockIdx.y * COT;
  const int cobase = co_blk + gu * COPT;
  const int ci_begin = (KSPLIT > 1) ? blockIdx.z * (CIN / KSPLIT) : 0;
  constexpr int NST = (CIN / KSPLIT) / CIT;

  float acc[COPT] = {};

  for (int st = 0; st < NST; ++st) {
    const int cib = ci_begin + st * CIT;
    if (st) __syncthreads();   // protect previous stage's reads
    // ---- staging: global float2 pairs -> interleaved EV|OD row layout ----
    for (int idx = tid; idx < NPAIR; idx += NTHR) {
      int ci = idx / (IH * EVW), rem = idx % (IH * EVW);
      int r = rem / EVW, c2 = rem % EVW;
      int iy = oy0 * 2 + r, ix = ox0 * 2 + 2 * c2;
      float v0 = 0.f, v1 = 0.f;
      const float* src = in + (size_t)(cib + ci) * HIN * WIN;
      if (iy < HIN) {
        if ((2 * c2 + 1 < IW) && (ix + 1 < WIN)) {
          float2 t = *(const float2*)(src + (size_t)iy * WIN + ix);
          v0 = t.x; v1 = t.y;
        } else if (ix < WIN) {
          v0 = src[(size_t)iy * WIN + ix];
        }
      }
      int rb = (ci * IH + r) * ROWW;
      lds[rb + c2] = v0;            // even col c2
      lds[rb + EVW + c2] = v1;      // odd col c2 (c2==SW -> pad slot)
    }
    __syncthreads();
    // ---- compute: 9 taps per ci from one base addr ----
#pragma unroll 2
    for (int ci = 0; ci < CIT; ++ci) {
      const int b0 = (ci * IH + 2 * py) * ROWW + px;
      float e00 = lds[b0];               // (kh0,kw0) col 2px
      float q0  = lds[b0 + EVW];         // (kh0,kw1) col 2px+1
      float e01 = lds[b0 + 1];           // (kh0,kw2) col 2px+2
      float e10 = lds[b0 + ROWW];
      float q1  = lds[b0 + ROWW + EVW];
      float e11 = lds[b0 + ROWW + 1];
      float e20 = lds[b0 + 2 * ROWW];
      float q2  = lds[b0 + 2 * ROWW + EVW];
      float e21 = lds[b0 + 2 * ROWW + 1];
      const float* wp = wr + (size_t)(cib + ci) * 9 * COUT + cobase;
#pragma unroll
      for (int c = 0; c < COPT; ++c) acc[c] = fmaf(e00, wp[c], acc[c]);
#pragma unroll
      for (int c = 0; c < COPT; ++c) acc[c] = fmaf(q0, wp[COUT + c], acc[c]);
#pragma unroll
      for (int c = 0; c < COPT; ++c) acc[c] = fmaf(e01, wp[2 * COUT + c], acc[c]);
#pragma unroll
      for (int c = 0; c < COPT; ++c) acc[c] = fmaf(e10, wp[3 * COUT + c], acc[c]);
#pragma unroll
      for (int c = 0; c < COPT; ++c) acc[c] = fmaf(q1, wp[4 * COUT + c], acc[c]);
#pragma unroll
      for (int c = 0; c < COPT; ++c) acc[c] = fmaf(e11, wp[5 * COUT + c], acc[c]);
#pragma unroll
      for (int c = 0; c < COPT; ++c) acc[c] = fmaf(e20, wp[6 * COUT + c], acc[c]);
#pragma unroll
      for (int c = 0; c < COPT; ++c) acc[c] = fmaf(q2, wp[7 * COUT + c], acc[c]);
#pragma unroll
      for (int c = 0; c < COPT; ++c) acc[c] = fmaf(e21, wp[8 * COUT + c], acc[c]);
    }
  }

  const int oy = oy0 + py, ox = ox0 + px;
#pragma unroll
  for (int c = 0; c < COPT; ++c) {
    int co = cobase + c;
    if constexpr (KSPLIT > 1) {
      out[((size_t)blockIdx.z * COUT + co) * (HOUT * WOUT) + oy * WOUT + ox] =
          acc[c];
    } else {
      out[(size_t)co * (HOUT * WOUT) + oy * WOUT + ox] =
          fmaxf(acc[c] + bias[co], 0.f);
    }
  }
}

// ---------------- combine conv4 K-split partials + bias + relu, write NHWC ---
// EXACT R0 semantics: v = ((p0+p1)+p2)+p3; out = max(v+b, 0)
__global__ __launch_bounds__(256) void k_combine(const float* __restrict__ part,
                                                 const float* __restrict__ b,
                                                 float* __restrict__ h4t) {
  int co = blockIdx.x;  // 0..255
  float bb = b[co];
  for (int k2 = 0; k2 < 4; ++k2) {
    int pos = threadIdx.x + k2 * 256;
    float v = part[(size_t)(0 * 256 + co) * 1024 + pos] +
              part[(size_t)(1 * 256 + co) * 1024 + pos] +
              part[(size_t)(2 * 256 + co) * 1024 + pos] +
              part[(size_t)(3 * 256 + co) * 1024 + pos];
    h4t[(size_t)pos * 256 + co] = fmaxf(v + bb, 0.f);
  }
}

// ---------------- head: reg(4)+cls(21) stride-1 conv + softmax/max/argmax ----
__global__ __launch_bounds__(256) void k_head(const float* __restrict__ h4t,
                                              const float* __restrict__ wh,
                                              const float* __restrict__ regb,
                                              const float* __restrict__ clsb,
                                              float* __restrict__ locs,
                                              float* __restrict__ confs,
                                              float* __restrict__ scores,
                                              float* __restrict__ labelsF) {
  const int pos = blockIdx.x;
  const int py = pos >> 5, px = pos & 31;
  const int t = threadIdx.x;
  float part[25] = {};
#pragma unroll
  for (int kh = 0; kh < 3; ++kh) {
    int iy = py + kh - 1;
    if (iy < 0 || iy > 31) continue;  // block-uniform
#pragma unroll
    for (int kw = 0; kw < 3; ++kw) {
      int ix = px + kw - 1;
      if (ix < 0 || ix > 31) continue;
      int tap = kh * 3 + kw;
      float v = h4t[(size_t)(iy * 32 + ix) * 256 + t];
      const float* wp = wh + (size_t)tap * 25 * 256 + t;
#pragma unroll
      for (int o = 0; o < 25; ++o)
        part[o] = fmaf(v, wp[(size_t)o * 256], part[o]);
    }
  }
#pragma unroll
  for (int o = 0; o < 25; ++o) {
#pragma unroll
    for (int d = 1; d < 64; d <<= 1) part[o] += __shfl_xor(part[o], d);
  }
  __shared__ float red[4][25];
  __shared__ float yv[25];
  const int wv = t >> 6, ln = t & 63;
  if (ln == 0) {
#pragma unroll
    for (int o = 0; o < 25; ++o) red[wv][o] = part[o];
  }
  __syncthreads();
  if (t < 25) {
    float y = red[0][t] + red[1][t] + red[2][t] + red[3][t];
    y += (t < 4) ? regb[t] : clsb[t - 4];
    if (t < 4) locs[(size_t)pos * 4 + t] = y;
    else       confs[(size_t)pos * 21 + (t - 4)] = y;
    yv[t] = y;
  }
  __syncthreads();
  if (t == 0) {
    float m = yv[4];
    int lab = 0;
    for (int j = 1; j < 21; ++j)
      if (yv[4 + j] > m) { m = yv[4 + j]; lab = j; }  // first-max semantics
    float s = 0.f;
    for (int j = 0; j < 21; ++j) s += expf(yv[4 + j] - m);
    scores[pos] = 1.f / s;   // max softmax prob
    labelsF[pos] = (float)lab;
  }
}

// ---------------- stable descending bitonic sort of 1024 scores --------------
__global__ __launch_bounds__(512) void k_sort(const float* __restrict__ scores,
                                              const float* __restrict__ locs,
                                              int* __restrict__ order,
                                              float* __restrict__ ssc,
                                              float* __restrict__ bsrt,
                                              unsigned long long* __restrict__ vbits) {
  __shared__ float sk[1024];
  __shared__ int   si[1024];
  const int t = threadIdx.x;
  sk[t] = scores[t];           si[t] = t;
  sk[t + 512] = scores[t + 512]; si[t + 512] = t + 512;
  for (int k = 2; k <= 1024; k <<= 1) {
    for (int j = k >> 1; j > 0; j >>= 1) {
      __syncthreads();
      int i1 = ((t / j) * (2 * j)) + (t % j);
      int i2 = i1 + j;
      bool up = (i1 & k) == 0;
      float sa = sk[i1], sb = sk[i2];
      int ia = si[i1], ib = si[i2];
      bool b_before_a = (sb > sa) || (sb == sa && ib < ia);
      bool a_before_b = (sa > sb) || (sa == sb && ia < ib);
      bool sw = up ? b_before_a : a_before_b;
      if (sw) { sk[i1] = sb; sk[i2] = sa; si[i1] = ib; si[i2] = ia; }
    }
  }
  __syncthreads();
  for (int i = t; i < 1024; i += 512) {
    int oi = si[i];
    order[i] = oi;
    ssc[i] = sk[i];
    ((float4*)bsrt)[i] = ((const float4*)locs)[oi];
  }
  if (t < 16) {  // validity bits (score > SCORE_THR), sorted order
    unsigned long long w = 0;
    for (int b2 = 0; b2 < 64; ++b2)
      if (sk[t * 64 + b2] > 0.04f) w |= (1ull << b2);
    vbits[t] = w;
  }
}

// ---------------- pairwise IoU suppression bitmask (1024x1024 bits) ----------
__global__ __launch_bounds__(256) void k_mask(const float* __restrict__ bsrt,
                                              unsigned long long* __restrict__ mask) {
  __shared__ float4 sb[1024];
  const int t = threadIdx.x;
  for (int idx = t; idx < 1024; idx += 256)
    sb[idx] = ((const float4*)bsrt)[idx];
  __syncthreads();
  const int i = blockIdx.x * 16 + (t & 15);
  const int w = t >> 4;
  float4 bi = sb[i];
  float ai = (bi.z - bi.x) * (bi.w - bi.y);
  unsigned long long bits = 0;
  for (int jj = 0; jj < 64; ++jj) {
    float4 bj = sb[w * 64 + jj];
    float aj = (bj.z - bj.x) * (bj.w - bj.y);
    float ltx = fmaxf(bi.x, bj.x), lty = fmaxf(bi.y, bj.y);
    float rbx = fminf(bi.z, bj.z), rby = fminf(bi.w, bj.w);
    float inter = fmaxf(rbx - ltx, 0.f) * fmaxf(rby - lty, 0.f);
    float uni = ai + aj - inter;
    float iou = inter / (uni + 1e-9f);
    if (iou > 0.5f) bits |= (1ull << jj);
  }
  mask[(size_t)i * 16 + w] = bits;
}

// ---------------- parallel fixpoint greedy NMS + fused gather ----------------
__global__ __launch_bounds__(1024) void k_nms_gather(
    const unsigned long long* __restrict__ mask,
    const unsigned long long* __restrict__ vbits,
    const int* __restrict__ order, const float* __restrict__ ssc,
    const float* __restrict__ locs, const float* __restrict__ confs,
    const float* __restrict__ labelsF, float* __restrict__ out) {
  __shared__ unsigned long long KEEP[16], DEAD[16];
  __shared__ int ncert;
  const int i = threadIdx.x;        // box index (sorted order)
  const int w = i >> 6, l = i & 63; // wave, lane

  unsigned long long R[16];
#pragma unroll
  for (int k = 0; k < 16; ++k) {
    unsigned long long m = 0;
    if (k < w) m = mask[(size_t)i * 16 + k];
    else if (k == w && l) m = mask[(size_t)i * 16 + k] & ((1ull << l) - 1ull);
    R[k] = m;
  }
  const bool valid = (vbits[w] >> l) & 1ull;

  if (i < 16) { KEEP[i] = 0ull; DEAD[i] = 0ull; }
  if (i == 0) ncert = 0;
  __syncthreads();

  int status = 0;  // 0 unknown, 1 kept, 2 dead
  for (;;) {
    unsigned long long s = 0, p = 0;
    if (status == 0) {
#pragma unroll
      for (int k = 0; k < 16; ++k) {
        unsigned long long K_ = KEEP[k], D_ = DEAD[k];
        s |= R[k] & K_;
        p |= R[k] & ~D_;
      }
    }
    __syncthreads();  // all reads done before any write
    bool newKeep = false, newDead = false;
    if (status == 0) {
      if (!valid)      { status = 2; newDead = true; }
      else if (s)      { status = 2; newDead = true; }
      else if (!p)     { status = 1; newKeep = true; }
    }
    unsigned long long bk = __ballot(newKeep);
    unsigned long long bd = __ballot(newDead);
    if (l == 0) {
      if (bk) KEEP[w] |= bk;
      if (bd) DEAD[w] |= bd;
      int n = __popcll(bk) + __popcll(bd);
      if (n) atomicAdd(&ncert, n);
    }
    __syncthreads();
    if (ncert >= 1024) break;
  }

  const bool kp = (status == 1);
  const int oi = order[i];
  float4 bx = kp ? ((const float4*)locs)[oi]
                 : make_float4(-1.f, -1.f, -1.f, -1.f);
  ((float4*)out)[i] = bx;
  out[4096 + i] = kp ? labelsF[oi] : 0.f;
  out[5120 + i] = kp ? ssc[i] : -1.f;
  float* oc = out + 6144 + (size_t)i * 21;
  const float* cc = confs + (size_t)oi * 21;
#pragma unroll
  for (int c = 0; c < 21; ++c) oc[c] = kp ? cc[c] : -1.f;
}

// ============================================================================
extern "C" void kernel_launch(void* const* d_in, const int* in_sizes, int n_in,
                              void* d_out, int out_size, void* d_ws, size_t ws_size,
                              hipStream_t stream) {
  const float* x    = (const float*)d_in[0] + (size_t)7 * 3 * 512 * 512;  // image 7
  const float* w1   = (const float*)d_in[1];
  const float* b1   = (const float*)d_in[2];
  const float* w2   = (const float*)d_in[3];
  const float* b2   = (const float*)d_in[4];
  const float* w3   = (const float*)d_in[5];
  const float* b3   = (const float*)d_in[6];
  const float* w4   = (const float*)d_in[7];
  const float* b4   = (const float*)d_in[8];
  const float* regw = (const float*)d_in[9];
  const float* regb = (const float*)d_in[10];
  const float* clsw = (const float*)d_in[11];
  const float* clsb = (const float*)d_in[12];
  float* out = (float*)d_out;
  char* ws = (char*)d_ws;

  // region A (0..16.8MB): h1, then part4 + h4t
  float* h1    = (float*)(ws + 0);          // 16.8MB  (dead after conv2)
  float* part4 = (float*)(ws + 0);          // 4MB     (dead after combine)
  float* h4t   = (float*)(ws + 9437184);    // 1MB
  float* h2    = (float*)(ws + 16777216);   // 8.4MB   (dead after conv3)
  float* h3    = (float*)(ws + 25165824);   // 4.2MB
  float* wr2   = (float*)(ws + 29360128);
  float* wr3   = (float*)(ws + 29655040);
  float* wr4   = (float*)(ws + 30834688);
  float* wh    = (float*)(ws + 33193984);
  float* locs  = (float*)(ws + 33424384);
  float* confs = (float*)(ws + 33440768);
  float* scores  = (float*)(ws + 33526784);
  float* labelsF = (float*)(ws + 33530880);
  int*   order   = (int*)  (ws + 33534976);
  float* ssc     = (float*)(ws + 33539072);
  float* bsrt    = (float*)(ws + 33543168);
  unsigned long long* mask  = (unsigned long long*)(ws + 33559552);
  unsigned long long* vbits = (unsigned long long*)(ws + 33690624);

  k_repack_all<<<3969, 256, 0, stream>>>(w2, w3, w4, regw, clsw,
                                         wr2, wr3, wr4, wh);

  k_conv1<<<dim3(16, 16, 4), dim3(16, 16), 0, stream>>>(x, w1, b1, h1);

  // conv2: COPT=8, 256 sp x 4 co = 1024 blocks x 256 thr, ROWW=36
  conv_s2<64, 128, 256, 256, 4, 16, 8, 16, 1, 36, 4>
      <<<dim3(256, 4, 1), 256, 0, stream>>>(h1, wr2, b2, h2);
  // conv3: COPT=4, 64 sp x 16 co = 1024 blocks, ROWW=20, 16 waves/CU
  conv_s2<128, 256, 128, 128, 8, 8, 4, 16, 1, 20, 4>
      <<<dim3(64, 16, 1), 256, 0, stream>>>(h2, wr3, b3, h3);
  // conv4: COPT=4, KSPLIT=4. 16 sp x 16 co x 4 = 1024 blocks, ROWW=20
  conv_s2<256, 256, 64, 64, 8, 8, 4, 16, 4, 20, 4>
      <<<dim3(16, 16, 4), 256, 0, stream>>>(h3, wr4, (const float*)nullptr, part4);
  k_combine<<<256, 256, 0, stream>>>(part4, b4, h4t);

  k_head<<<1024, 256, 0, stream>>>(h4t, wh, regb, clsb, locs, confs, scores, labelsF);

  k_sort<<<1, 512, 0, stream>>>(scores, locs, order, ssc, bsrt, vbits);
  k_mask<<<64, 256, 0, stream>>>(bsrt, mask);
  k_nms_gather<<<1, 1024, 0, stream>>>(mask, vbits, order, ssc, locs, confs,
                                       labelsF, out);
}